// Round 14
// baseline (6681.291 us; speedup 1.0000x reference)
//
#include <hip/hip_runtime.h>
#include <stdint.h>

#define T_ 2000
#define B_ 64
#define S_ 128
#define HASHM 1000003u

typedef float f4 __attribute__((ext_vector_type(4)));
typedef int i2v __attribute__((ext_vector_type(2)));

#if defined(__has_builtin)
#if __has_builtin(__builtin_amdgcn_permlane32_swap)
#define HAVE_PL32 1
#endif
#if __has_builtin(__builtin_amdgcn_permlane16_swap)
#define HAVE_PL16 1
#endif
#endif

__device__ __forceinline__ uint32_t rl(uint32_t v, int ln) {
  return (uint32_t)__builtin_amdgcn_readlane((int)v, ln);
}
__device__ __forceinline__ float rlf(float v, int ln) {
  return __uint_as_float(rl(__float_as_uint(v), ln));
}

// float -> order-preserving u32 (handles -1.0 sentinels; else nonneg)
__device__ __forceinline__ uint32_t fkey(float v) {
  uint32_t b = __float_as_uint(v);
  return b ^ (((int32_t)b < 0) ? 0xFFFFFFFFu : 0x80000000u);
}

// butterfly partner exchange (value of lane^J) — ALL VALU, no LDS pipe.
template<int J>
__device__ __forceinline__ uint32_t bfly_u32(uint32_t v) {
  if constexpr (J == 1)
    return (uint32_t)__builtin_amdgcn_update_dpp((int)v, (int)v, 0xB1, 0xF, 0xF, false);
  else if constexpr (J == 2)
    return (uint32_t)__builtin_amdgcn_update_dpp((int)v, (int)v, 0x4E, 0xF, 0xF, false);
  else if constexpr (J == 4) {
    uint32_t a = (uint32_t)__builtin_amdgcn_update_dpp((int)v, (int)v, 0x12C, 0xF, 0xF, false); // ror:12
    uint32_t b = (uint32_t)__builtin_amdgcn_update_dpp((int)v, (int)v, 0x124, 0xF, 0xF, false); // ror:4
    return ((threadIdx.x & 4) == 0) ? a : b;
  } else if constexpr (J == 8)
    return (uint32_t)__builtin_amdgcn_update_dpp((int)v, (int)v, 0x128, 0xF, 0xF, false); // ror:8 == xor 8
  else if constexpr (J == 16) {
#ifdef HAVE_PL16
    i2v r = __builtin_amdgcn_permlane16_swap((int)v, (int)v, false, false);
    return (uint32_t)(((threadIdx.x & 16) == 0) ? r[1] : r[0]);
#else
    return (uint32_t)__builtin_amdgcn_ds_swizzle((int)v, 0x401F);
#endif
  } else {  // J == 32
#ifdef HAVE_PL32
    i2v r = __builtin_amdgcn_permlane32_swap((int)v, (int)v, false, false);
    return (uint32_t)(((threadIdx.x & 32) == 0) ? r[1] : r[0]);
#else
    return (uint32_t)__shfl_xor((int)v, 32);
#endif
  }
}
template<int J>
__device__ __forceinline__ uint64_t bfly_u64(uint64_t v) {
  uint32_t lo = bfly_u32<J>((uint32_t)v);
  uint32_t hi = bfly_u32<J>((uint32_t)(v >> 32));
  return ((uint64_t)hi << 32) | lo;
}
template<int J>
__device__ __forceinline__ float bfly_f32(float v) {
  return __uint_as_float(bfly_u32<J>(__float_as_uint(v)));
}

#define BSTF(KK, J) { float p_ = __uint_as_float(bfly_u32<J>(__float_as_uint(v))); \
  bool d_ = ((ln & (KK)) == 0) == ((ln & (J)) == 0); \
  float mx_ = fmaxf(v, p_), mn_ = fminf(v, p_); v = d_ ? mx_ : mn_; }

// u64 compare-exchange via f64 min/max: survivor packs have bit63==0 and
// f64-exponent field < 0x7FF (keys are finite nonneg f32 bits), so f64
// IEEE ordering == u64 ordering (f64 denormals are always-IEEE on AMDGPU;
// the 0ull padding is f64 +0.0 and sorts below all denormals, matching u64).
// NOT valid for fkey-space values (bit63 set).
#define BST64(KK, J) { uint64_t p_ = bfly_u64<J>(v); \
  bool d_ = ((ln & (KK)) == 0) == ((ln & (J)) == 0); \
  double vd_ = __longlong_as_double((long long)v); \
  double pd_ = __longlong_as_double((long long)p_); \
  double mx_ = fmax(vd_, pd_), mn_ = fmin(vd_, pd_); \
  v = (uint64_t)__double_as_longlong(d_ ? mx_ : mn_); }

// full-wave descending bitonic sort of floats (no NaNs; -1.0 sentinels ok)
// — used only in the rare M>64 refine branch.
__device__ __forceinline__ float bsort64_f32(float v, const int ln) {
  BSTF(2, 1)
  BSTF(4, 2) BSTF(4, 1)
  BSTF(8, 4) BSTF(8, 2) BSTF(8, 1)
  BSTF(16, 8) BSTF(16, 4) BSTF(16, 2) BSTF(16, 1)
  BSTF(32, 16) BSTF(32, 8) BSTF(32, 4) BSTF(32, 2) BSTF(32, 1)
  BSTF(64, 32) BSTF(64, 16) BSTF(64, 8) BSTF(64, 4) BSTF(64, 2) BSTF(64, 1)
  return v;
}

// 15-stage partial bitonic: lanes 0-31 sorted DESCENDING, lanes 32-63
// ASCENDING ((ln&KK)==0 => descending per BSTF) — i.e. one bitonic-64.
__device__ __forceinline__ float bsort_halves_f32(float v, const int ln) {
  BSTF(2, 1)
  BSTF(4, 2) BSTF(4, 1)
  BSTF(8, 4) BSTF(8, 2) BSTF(8, 1)
  BSTF(16, 8) BSTF(16, 4) BSTF(16, 2) BSTF(16, 1)
  BSTF(32, 16) BSTF(32, 8) BSTF(32, 4) BSTF(32, 2) BSTF(32, 1)
  return v;
}

// descending bitonic sort of u64, width 16/32/64 (sub-width groups sort
// independently; only lanes 0..15 are consumed downstream)
template<int WIDTH>
__device__ __forceinline__ uint64_t bsortN_u64(uint64_t v, const int ln) {
  BST64(2, 1)
  BST64(4, 2) BST64(4, 1)
  BST64(8, 4) BST64(8, 2) BST64(8, 1)
  BST64(16, 8) BST64(16, 4) BST64(16, 2) BST64(16, 1)
  if constexpr (WIDTH >= 32) {
    BST64(32, 16) BST64(32, 8) BST64(32, 4) BST64(32, 2) BST64(32, 1)
  }
  if constexpr (WIDTH >= 64) {
    BST64(64, 32) BST64(64, 16) BST64(64, 8) BST64(64, 4) BST64(64, 2) BST64(64, 1)
  }
  return v;
}

__device__ __forceinline__ uint32_t incl_scan_add(uint32_t v) {
  v += (uint32_t)__builtin_amdgcn_update_dpp(0, (int)v, 0x111, 0xF, 0xF, false);
  v += (uint32_t)__builtin_amdgcn_update_dpp(0, (int)v, 0x112, 0xF, 0xF, false);
  v += (uint32_t)__builtin_amdgcn_update_dpp(0, (int)v, 0x114, 0xF, 0xF, false);
  v += (uint32_t)__builtin_amdgcn_update_dpp(0, (int)v, 0x118, 0xF, 0xF, false);
  v += (uint32_t)__builtin_amdgcn_update_dpp(0, (int)v, 0x142, 0xA, 0xF, false);
  v += (uint32_t)__builtin_amdgcn_update_dpp(0, (int)v, 0x143, 0xC, 0xF, false);
  return v;
}

// integer u64 max (fkey-space can set bit63; f64 trick NOT valid here)
template<int CTRL>
__device__ __forceinline__ uint64_t dpp_max_u64(uint64_t v) {
  uint32_t lo = (uint32_t)v, hi = (uint32_t)(v >> 32);
  uint32_t slo = (uint32_t)__builtin_amdgcn_update_dpp(0, (int)lo, CTRL, 0xF, 0xF, false);
  uint32_t shi = (uint32_t)__builtin_amdgcn_update_dpp(0, (int)hi, CTRL, 0xF, 0xF, false);
  uint64_t o = ((uint64_t)shi << 32) | slo;
  return (o > v) ? o : v;
}
__device__ __forceinline__ uint64_t wave_max_u64(uint64_t v) {
  v = dpp_max_u64<0x111>(v);
  v = dpp_max_u64<0x112>(v);
  v = dpp_max_u64<0x114>(v);
  v = dpp_max_u64<0x118>(v);
  v = dpp_max_u64<0x142>(v);
  v = dpp_max_u64<0x143>(v);
  uint32_t lo = rl((uint32_t)v, 63);
  uint32_t hi = rl((uint32_t)(v >> 32), 63);
  return ((uint64_t)hi << 32) | lo;
}

// One wave per batch element. Beam m's state in lanes with (lane&15)==m
// (replicated 4x). Candidate slot (lane = m+16g, k): symbol c = 32g+k,
// except (g=0,k=0) = unchanged candidate of beam m. 2048 slots exactly.
// DS ordering: per-wave LDS ops execute in order and the compiler keeps
// program order for same-object accesses + inserts counted lgkmcnt waits.
// Merge gather (the only unprefetchable DS on the spine) is issued right
// after detect; kf[1..31] + the max tree (gather-independent) execute
// under its latency; slot-0 (key16) folds in afterward — m1 is bit-exact
// (fmax is order-independent on non-NaN).
__global__ __launch_bounds__(64, 1) void ctc_decode_kernel(
    const float* __restrict__ x, const int* __restrict__ lengths,
    float* __restrict__ out) {
  __shared__ uint64_t surv[64];              // 64 survivors (dump goes to trace)
  __shared__ __align__(16) float Pr[S_];     // pruned probs (single buffer)
  __shared__ __align__(16) uint32_t bstH[32];  // {h_j, h_j*HASHM} pairs
  __shared__ __align__(16) uint32_t bstD[16][4];  // {h, lpack, c0pb, upnb}
  __shared__ __align__(8) uint16_t trace[T_ * 16];  // (parent<<8)|sym per step/beam

  const int b = blockIdx.x;
  const int lane = (int)threadIdx.x;
  const int m = lane & 15;
  const int g = lane >> 4;
  const int lenb = lengths[b];

  uint32_t h = (m == 0) ? 0u : (0x80000000u + (uint32_t)m);
  uint32_t hMreg = h * HASHM;   // loop-carried own-beam h*HASHM
  float pb = (m == 0) ? 1.0f : 0.0f;
  float pnb = 0.0f;
  int last = -1;
  int len = 0;

  // t = 0: load + stage into Pr; prefetch pv/plast; publish bstH
  float plast;
  f4 pv[8];
  {
    const float* xt = x + (size_t)b * S_;
    float a0 = xt[lane], a1 = xt[lane + 64];
    float p0 = (a0 > 0.001f) ? a0 : 0.0f;
    float p1 = (a1 > 0.001f) ? a1 : 0.0f;
    Pr[lane] = p0;
    Pr[lane + 64] = p1;
    if (lane < 16) {
      uint2 w2; w2.x = h; w2.y = hMreg;
      *(uint2*)&bstH[2 * m] = w2;
    }
    const f4* P4 = (const f4*)(Pr + 32 * g);
    #pragma unroll
    for (int i = 0; i < 8; ++i) pv[i] = P4[i];
    plast = Pr[0];  // last == -1 -> index 0
  }

  const uint32_t cbase = 1u + 32u * (uint32_t)g;
  const uint32_t nrefb = ~(15u + (uint32_t)m * 127u + 32u * (uint32_t)g);

  for (int t = 0; t < lenb; ++t) {
    const float* P = Pr;
    // ---- step-top LDS reads (broadcast, pipelined via counted lgkmcnt)
    uint4 hq[8];
    #pragma unroll
    for (int i = 0; i < 8; ++i) hq[i] = ((const uint4*)bstH)[i];
    const float P0 = P[0];
    // prefetch next frame (raw; pruning + staging happen late this step)
    float r0n = 0.0f, r1n = 0.0f;
    const bool hasNext = (t + 1 < lenb);
    if (hasNext) {
      const float* xt = x + ((size_t)(t + 1) * B_ + b) * S_;
      r0n = xt[lane];
      r1n = xt[lane + 64];
    }
    const uint32_t hMc = hMreg + cbase;

    const float ptot = __fadd_rn(pb, pnb);
    const float c0pb = __fmul_rn(P0, ptot);
    const float c0pnb = (last >= 0) ? __fmul_rn(plast, pnb) : 0.0f;

    // ---- fused dup-mask + merge-match detection (register h/hM vectors)
    uint32_t lmask = 0;
    uint32_t matchcnt = 0, jm = 0, cc = 1;
    #pragma unroll
    for (int j = 0; j < 16; ++j) {
      const uint32_t s_h  = (j & 1) ? hq[j >> 1].z : hq[j >> 1].x;
      const uint32_t s_hM = (j & 1) ? hq[j >> 1].w : hq[j >> 1].y;
      // dup: beam j's hash equals my ext (symbol c = s_h - hM - 1)
      uint32_t p = s_h - hMc;
      lmask |= (p < 32u) ? (1u << (p & 31u)) : 0u;
      // merge: my hash equals an ext of beam j
      uint32_t d = h - s_hM;
      bool match = (d - 2u) <= 126u;
      cc = match ? (d - 1u) : cc;
      jm = match ? (uint32_t)j : jm;
      matchcnt += match ? 1u : 0u;
    }
    const bool multi = (__ballot(matchcnt > 1u) != 0ull);

    // ---- issue single-match merge gather NOW; its latency hides under the
    // kf[1..31] build + max tree below (slot-0 folds in afterward).
    float tv = P[cc];                       // DS read
    float tpb = __shfl(pb, (int)jm);        // DS (bpermute)
    float tpt = __shfl(ptot, (int)jm);
    int tlast = __shfl(last, (int)jm);

    // ---- build 32 candidate keys (floats; dup -> -1.0 sentinel).
    // kf[0] holds the RAW slot value; the lane<16 key16 override happens
    // after the merge term is finalized (before count/compress).
    const int lk = last - 32 * g;
    float kf[32];
    #pragma unroll
    for (int k = 0; k < 32; ++k) {
      float pc = pv[k >> 2][k & 3];
      float sel = (k == lk) ? pb : ptot;
      float val = __fmul_rn(pc, sel);
      bool dup = (lmask >> k) & 1u;
      kf[k] = dup ? -1.0f : val;
    }

    // ---- per-lane max tree over kf[1..31] (gather-independent)
    float mx[16];
    #pragma unroll
    for (int i = 0; i < 15; ++i) mx[i] = fmaxf(kf[2 * i + 1], kf[2 * i + 2]);
    mx[15] = kf[31];
    #pragma unroll
    for (int w2 = 8; w2 >= 1; w2 >>= 1) {
      #pragma unroll
      for (int i = 0; i < w2; ++i) mx[i] = fmaxf(mx[i], mx[i + w2]);
    }

    // ---- merge term finalize (gather landed during the tree)
    float term0;
    if (__builtin_expect(!multi, 1)) {
      float sel = ((int)cc == tlast) ? tpb : tpt;
      term0 = (matchcnt != 0u) ? __fmul_rn(tv, sel) : 0.0f;
    } else {
      // exact multi-match path (identical to verified full gather + tree)
      float term[16];
      #pragma unroll
      for (int j = 0; j < 16; ++j) {
        uint32_t s_h = rl(h, j);
        uint32_t d = h - s_h * HASHM;
        bool match2 = (d - 2u) <= 126u;
        uint32_t cc2 = match2 ? (d - 1u) : 1u;
        float tv2 = P[cc2];
        uint32_t slst = rl((uint32_t)last, j);
        float sel = (cc2 == slst) ? rlf(pb, j) : rlf(ptot, j);
        term[j] = match2 ? __fmul_rn(tv2, sel) : 0.0f;
      }
      #pragma unroll
      for (int st = 1; st < 16; st <<= 1) {
        #pragma unroll
        for (int i2 = 0; i2 < 16; i2 += 2 * st)
          term[i2] = __fadd_rn(term[i2], term[i2 + st]);
      }
      term0 = term[0];
    }
    const float upnb = __fadd_rn(c0pnb, term0);
    const float key16 = __fadd_rn(c0pb, upnb);

    // ---- publish decode-state now (consumed ~400cy later by decode; all
    // four values are per-beam uniform across the 4 replica lanes)
    if (lane < 16) {
      uint4 w4;
      w4.x = h;
      w4.y = ((uint32_t)(last + 1) & 0xFFu) | ((uint32_t)len << 8);
      w4.z = __float_as_uint(c0pb);
      w4.w = __float_as_uint(upnb);
      *(uint4*)&bstD[m][0] = w4;
    }

    // ---- fold slot-0 into the lane max (fmax order-independent: bit-exact)
    const float slot0 = (lane < 16) ? key16 : kf[0];
    kf[0] = slot0;
    const float m1 = fmaxf(mx[0], slot0);

    // ---- theta: 15-stage half-sort -> bitonic-64; two half-cleaners give
    // the top-16 multiset replicated in EVERY 16-row; th = row-min = exact
    // rank-15 (bit-identical to the full sort), gmx = row-max = rank-0.
    // No readlane: th and scale end up wave-uniform in VGPRs.
    const float hv = bsort_halves_f32(m1, lane);
    const float c1 = fmaxf(hv, bfly_f32<32>(hv));   // top-32 multiset (repl.)
    const float c2 = fmaxf(c1, bfly_f32<16>(c1));   // top-16 multiset (repl.)
    float mn = c2, mxr = c2;
    mn = fminf(mn, bfly_f32<1>(mn));  mxr = fmaxf(mxr, bfly_f32<1>(mxr));
    mn = fminf(mn, bfly_f32<2>(mn));  mxr = fmaxf(mxr, bfly_f32<2>(mxr));
    mn = fminf(mn, bfly_f32<4>(mn));  mxr = fmaxf(mxr, bfly_f32<4>(mxr));
    mn = fminf(mn, bfly_f32<8>(mn));  mxr = fmaxf(mxr, bfly_f32<8>(mxr));
    float th = mn;

    // ---- rescale divisor (global max candidate; uniform, no readlane)
    const float mxf = fmaxf(mxr, 1e-30f);
    const float scale = __fdiv_rn(1.0f, mxf);

    uint32_t gcnt[4];
    #pragma unroll
    for (int grp = 0; grp < 4; ++grp) {
      uint32_t c2c = 0;
      #pragma unroll
      for (int k = grp * 8; k < grp * 8 + 8; ++k) c2c += (kf[k] >= th) ? 1u : 0u;
      gcnt[grp] = c2c;
    }
    uint32_t cnt = (gcnt[0] + gcnt[1]) + (gcnt[2] + gcnt[3]);
    uint32_t incl = incl_scan_add(cnt);
    uint32_t M = rl(incl, 63);

    // ---- refine: theta2 = 8th-largest m2 (8 lanes x top-2 => >=16 >= th2)
    if (__builtin_expect(M > 64u, 0)) {
      // per-lane top-2 tournament (2nd = max3(min(h1,h2), s1, s2))
      float t1[16], t2[16];
      #pragma unroll
      for (int i = 0; i < 16; ++i) {
        float a2 = kf[2 * i], b2 = kf[2 * i + 1];
        t1[i] = fmaxf(a2, b2);
        t2[i] = fminf(a2, b2);
      }
      #pragma unroll
      for (int w2 = 8; w2 >= 1; w2 >>= 1) {
        #pragma unroll
        for (int i = 0; i < w2; ++i) {
          float A = t1[i], Bv = t1[i + w2];
          float sa = t2[i], sb = t2[i + w2];
          t1[i] = fmaxf(A, Bv);
          t2[i] = fmaxf(fminf(A, Bv), fmaxf(sa, sb));
        }
      }
      float th2 = rlf(bsort64_f32(t2[0], lane), 7);
      th = fmaxf(th, th2);
      #pragma unroll
      for (int grp = 0; grp < 4; ++grp) {
        uint32_t c2c = 0;
        #pragma unroll
        for (int k = grp * 8; k < grp * 8 + 8; ++k) c2c += (kf[k] >= th) ? 1u : 0u;
        gcnt[grp] = c2c;
      }
      cnt = (gcnt[0] + gcnt[1]) + (gcnt[2] + gcnt[3]);
      incl = incl_scan_add(cnt);
      M = rl(incl, 63);
    }

    uint64_t selpk;
    if (__builtin_expect(M <= 64u, 1)) {
      // ---- branchless compress into LDS; 4 independent 8-deep pos chains.
      // Dump target = this step's trace region (fully overwritten below).
      uint64_t* dump = (uint64_t*)(&trace[(size_t)t * 16]);
      uint32_t base0 = incl - cnt;
      uint32_t base1 = base0 + gcnt[0];
      uint32_t base2 = base1 + gcnt[1];
      uint32_t base3 = base2 + gcnt[2];
      uint32_t bases[4] = {base0, base1, base2, base3};
      #pragma unroll
      for (int grp = 0; grp < 4; ++grp) {
        uint32_t pos = bases[grp];
        #pragma unroll
        for (int kk = 0; kk < 8; ++kk) {
          int k = grp * 8 + kk;
          bool q = kf[k] >= th;
          uint32_t nr = nrefb - (uint32_t)k;
          if (k == 0) nr = (lane < 16) ? ~(uint32_t)m : nr;
          uint64_t pk = ((uint64_t)__float_as_uint(kf[k]) << 32) | nr;
          uint64_t* dst = q ? &surv[pos] : dump;  // pos < M <= 64 when q
          *dst = pk;
          pos += q ? 1u : 0u;
        }
      }
      // No fence: surv read below may-alias the writes, so the compiler
      // keeps order and emits the counted lgkmcnt; DS pipe is in-order.
      uint64_t w = ((uint32_t)lane < M) ? surv[lane] : 0ull;
      if (M <= 16u)      w = bsortN_u64<16>(w, lane);
      else if (M <= 32u) w = bsortN_u64<32>(w, lane);
      else               w = bsortN_u64<64>(w, lane);
      // broadcast ranks 0..15 (row 0) to all rows: lane gets rank (lane&15)
      uint64_t s16 = bfly_u64<16>(w);
      uint64_t w01 = ((lane & 16) == 0) ? w : s16;
      uint64_t s32 = bfly_u64<32>(w01);
      selpk = ((lane & 32) == 0) ? w01 : s32;
    } else {
      // last-resort exact fallback: 16 rounds of argmax with removal
      uint32_t alive = 0xFFFFFFFFu;
      selpk = 0;
      #pragma unroll 1
      for (int r = 0; r < 16; ++r) {
        float bk = -1.0f;
        uint32_t bi = 0;
        #pragma unroll
        for (int k = 0; k < 32; ++k) {
          float kv = ((alive >> k) & 1u) ? kf[k] : -1.0f;
          if (kv > bk) { bk = kv; bi = (uint32_t)k; }
        }
        uint32_t nr = nrefb - bi;
        nr = (bi == 0u && lane < 16) ? ~(uint32_t)m : nr;
        uint64_t cand = ((uint64_t)fkey(bk) << 32) | nr;
        uint64_t win = wave_max_u64(cand);
        if (cand == win) alive &= ~(1u << bi);
        if (r == m) selpk = win;
      }
      // repack winner key from fkey-space to raw float bits
      uint32_t kb = (uint32_t)(selpk >> 32);
      kb ^= ((int32_t)kb < 0) ? 0x80000000u : 0xFFFFFFFFu;
      selpk = ((uint64_t)kb << 32) | (uint32_t)selpk;
    }

    // ---- stage next frame (in-order DS; all frame-t reads — P0, P[cc],
    //      multi-match gathers — were issued earlier in program order)
    if (hasNext) {
      float p0 = (r0n > 0.001f) ? r0n : 0.0f;
      float p1 = (r1n > 0.001f) ? r1n : 0.0f;
      Pr[lane] = p0;
      Pr[lane + 64] = p1;
    }

    // ---- decode winner -> new beam m state (single b128 gather from bstD)
    const uint32_t gref = ~((uint32_t)selpk);
    const uint32_t keyw = (uint32_t)(selpk >> 32);
    const bool unch = gref < 16u;
    const uint32_t qq = gref - 16u;
    const uint32_t bsrc = qq / 127u;
    const uint32_t jj = qq - bsrc * 127u;
    const uint32_t c = jj + 1u;
    const int srcl = unch ? (int)gref : (int)bsrc;

    const uint4 sd = *(const uint4*)&bstD[srcl][0];
    const uint32_t s_h = sd.x;
    const int s_lst = (int)(sd.y & 0xFFu) - 1;
    const int s_len = (int)(sd.y >> 8);
    const float s_upb = __uint_as_float(sd.z);
    const float s_upn = __uint_as_float(sd.w);

    const uint32_t n_h = unch ? s_h : (s_h * HASHM + (jj + 2u));
    const uint32_t n_hM = n_h * HASHM;
    const float n_pb = unch ? s_upb : 0.0f;
    const float n_pnb = unch ? s_upn : __uint_as_float(keyw);
    const int n_last = unch ? s_lst : (int)c;
    const int n_len = unch ? s_len : (s_len + 1);

    // publish next-step beam hashes (read ~150cy later at next step top)
    if (lane < 16) {
      uint2 w2; w2.x = n_h; w2.y = n_hM;
      *(uint2*)&bstH[2 * m] = w2;
      trace[t * 16 + lane] =
          (uint16_t)(((uint32_t)srcl << 8) | (unch ? 0u : c));
    }

    // ---- rescale (exact, scale precomputed from the theta reduce)
    pb = __fmul_rn(n_pb, scale);
    pnb = __fmul_rn(n_pnb, scale);
    h = n_h; hMreg = n_hM; last = n_last; len = n_len;

    // ---- cross-step prefetch: next step's LDS frame reads issued here so
    // their latency hides under the loop tail + next step's head VALU.
    // Single buffer is safe: staging above already wrote frame t+1, and
    // in-order DS means these reads observe it.
    if (hasNext) {
      const f4* Pn4 = (const f4*)(Pr + 32 * g);
      #pragma unroll
      for (int i = 0; i < 8; ++i) pv[i] = Pn4[i];
      plast = Pr[(last >= 0) ? last : 0];
    }
  }

  __syncthreads();

  float* prefs = out;
  float* lensOut = out + (B_ * T_);
  float* scores = out + (B_ * T_) + B_;

  const int L0 = __shfl(len, 0);
  for (int i = L0 + lane; i < T_; i += 64) prefs[(size_t)b * T_ + i] = -1.0f;

  if (lane == 0) {
    lensOut[b] = (float)L0;
    scores[b] = __fadd_rn(pb, pnb);
    int w = 0;
    int pos2 = L0 - 1;
    for (int t2 = lenb - 1; t2 >= 0; --t2) {
      uint32_t rec = trace[t2 * 16 + w];
      uint32_t sym = rec & 0xFFu;
      if (sym) { prefs[(size_t)b * T_ + pos2] = (float)sym; --pos2; }
      w = (int)(rec >> 8);
    }
  }
}

extern "C" void kernel_launch(void* const* d_in, const int* in_sizes, int n_in,
                              void* d_out, int out_size, void* d_ws, size_t ws_size,
                              hipStream_t stream) {
  (void)in_sizes; (void)n_in; (void)d_ws; (void)ws_size; (void)out_size;
  const float* x = (const float*)d_in[0];
  const int* lengths = (const int*)d_in[1];
  float* out = (float*)d_out;
  ctc_decode_kernel<<<B_, 64, 0, stream>>>(x, lengths, out);
}

// Round 15
// 6456.250 us; speedup vs baseline: 1.0349x; 1.0349x over previous
//
#include <hip/hip_runtime.h>
#include <stdint.h>

#define T_ 2000
#define B_ 64
#define S_ 128
#define HASHM 1000003u

typedef float f4 __attribute__((ext_vector_type(4)));
typedef int i2v __attribute__((ext_vector_type(2)));

#if defined(__has_builtin)
#if __has_builtin(__builtin_amdgcn_permlane32_swap)
#define HAVE_PL32 1
#endif
#if __has_builtin(__builtin_amdgcn_permlane16_swap)
#define HAVE_PL16 1
#endif
#endif

__device__ __forceinline__ uint32_t rl(uint32_t v, int ln) {
  return (uint32_t)__builtin_amdgcn_readlane((int)v, ln);
}
__device__ __forceinline__ float rlf(float v, int ln) {
  return __uint_as_float(rl(__float_as_uint(v), ln));
}

// float -> order-preserving u32 (handles -1.0 sentinels; else nonneg)
__device__ __forceinline__ uint32_t fkey(float v) {
  uint32_t b = __float_as_uint(v);
  return b ^ (((int32_t)b < 0) ? 0xFFFFFFFFu : 0x80000000u);
}

// butterfly partner exchange (value of lane^J) — ALL VALU, no LDS pipe.
template<int J>
__device__ __forceinline__ uint32_t bfly_u32(uint32_t v) {
  if constexpr (J == 1)
    return (uint32_t)__builtin_amdgcn_update_dpp((int)v, (int)v, 0xB1, 0xF, 0xF, false);
  else if constexpr (J == 2)
    return (uint32_t)__builtin_amdgcn_update_dpp((int)v, (int)v, 0x4E, 0xF, 0xF, false);
  else if constexpr (J == 4) {
    uint32_t a = (uint32_t)__builtin_amdgcn_update_dpp((int)v, (int)v, 0x12C, 0xF, 0xF, false); // ror:12
    uint32_t b = (uint32_t)__builtin_amdgcn_update_dpp((int)v, (int)v, 0x124, 0xF, 0xF, false); // ror:4
    return ((threadIdx.x & 4) == 0) ? a : b;
  } else if constexpr (J == 8)
    return (uint32_t)__builtin_amdgcn_update_dpp((int)v, (int)v, 0x128, 0xF, 0xF, false); // ror:8 == xor 8
  else if constexpr (J == 16) {
#ifdef HAVE_PL16
    i2v r = __builtin_amdgcn_permlane16_swap((int)v, (int)v, false, false);
    return (uint32_t)(((threadIdx.x & 16) == 0) ? r[1] : r[0]);
#else
    return (uint32_t)__builtin_amdgcn_ds_swizzle((int)v, 0x401F);
#endif
  } else {  // J == 32
#ifdef HAVE_PL32
    i2v r = __builtin_amdgcn_permlane32_swap((int)v, (int)v, false, false);
    return (uint32_t)(((threadIdx.x & 32) == 0) ? r[1] : r[0]);
#else
    return (uint32_t)__shfl_xor((int)v, 32);
#endif
  }
}
template<int J>
__device__ __forceinline__ uint64_t bfly_u64(uint64_t v) {
  uint32_t lo = bfly_u32<J>((uint32_t)v);
  uint32_t hi = bfly_u32<J>((uint32_t)(v >> 32));
  return ((uint64_t)hi << 32) | lo;
}
template<int J>
__device__ __forceinline__ float bfly_f32(float v) {
  return __uint_as_float(bfly_u32<J>(__float_as_uint(v)));
}

#define BSTF(KK, J) { float p_ = __uint_as_float(bfly_u32<J>(__float_as_uint(v))); \
  bool d_ = ((ln & (KK)) == 0) == ((ln & (J)) == 0); \
  float mx_ = fmaxf(v, p_), mn_ = fminf(v, p_); v = d_ ? mx_ : mn_; }

// u64 compare-exchange via f64 min/max: survivor packs have bit63==0 and
// f64-exponent field < 0x7FF (keys are finite nonneg f32 bits), so f64
// IEEE ordering == u64 ordering (f64 denormals are always-IEEE on AMDGPU;
// the 0ull padding is f64 +0.0 and sorts below all denormals, matching u64).
// NOT valid for fkey-space values (bit63 set).
#define BST64(KK, J) { uint64_t p_ = bfly_u64<J>(v); \
  bool d_ = ((ln & (KK)) == 0) == ((ln & (J)) == 0); \
  double vd_ = __longlong_as_double((long long)v); \
  double pd_ = __longlong_as_double((long long)p_); \
  double mx_ = fmax(vd_, pd_), mn_ = fmin(vd_, pd_); \
  v = (uint64_t)__double_as_longlong(d_ ? mx_ : mn_); }

// full-wave descending bitonic sort of floats (no NaNs; -1.0 sentinels ok)
// — used only in the rare M>64 refine branch.
__device__ __forceinline__ float bsort64_f32(float v, const int ln) {
  BSTF(2, 1)
  BSTF(4, 2) BSTF(4, 1)
  BSTF(8, 4) BSTF(8, 2) BSTF(8, 1)
  BSTF(16, 8) BSTF(16, 4) BSTF(16, 2) BSTF(16, 1)
  BSTF(32, 16) BSTF(32, 8) BSTF(32, 4) BSTF(32, 2) BSTF(32, 1)
  BSTF(64, 32) BSTF(64, 16) BSTF(64, 8) BSTF(64, 4) BSTF(64, 2) BSTF(64, 1)
  return v;
}

// 15-stage partial bitonic: lanes 0-31 sorted DESCENDING, lanes 32-63
// ASCENDING ((ln&KK)==0 => descending per BSTF) — i.e. one bitonic-64.
__device__ __forceinline__ float bsort_halves_f32(float v, const int ln) {
  BSTF(2, 1)
  BSTF(4, 2) BSTF(4, 1)
  BSTF(8, 4) BSTF(8, 2) BSTF(8, 1)
  BSTF(16, 8) BSTF(16, 4) BSTF(16, 2) BSTF(16, 1)
  BSTF(32, 16) BSTF(32, 8) BSTF(32, 4) BSTF(32, 2) BSTF(32, 1)
  return v;
}

// descending bitonic sort of u64, width 16/32/64 (sub-width groups sort
// independently; only lanes 0..15 are consumed downstream)
template<int WIDTH>
__device__ __forceinline__ uint64_t bsortN_u64(uint64_t v, const int ln) {
  BST64(2, 1)
  BST64(4, 2) BST64(4, 1)
  BST64(8, 4) BST64(8, 2) BST64(8, 1)
  BST64(16, 8) BST64(16, 4) BST64(16, 2) BST64(16, 1)
  if constexpr (WIDTH >= 32) {
    BST64(32, 16) BST64(32, 8) BST64(32, 4) BST64(32, 2) BST64(32, 1)
  }
  if constexpr (WIDTH >= 64) {
    BST64(64, 32) BST64(64, 16) BST64(64, 8) BST64(64, 4) BST64(64, 2) BST64(64, 1)
  }
  return v;
}

__device__ __forceinline__ uint32_t incl_scan_add(uint32_t v) {
  v += (uint32_t)__builtin_amdgcn_update_dpp(0, (int)v, 0x111, 0xF, 0xF, false);
  v += (uint32_t)__builtin_amdgcn_update_dpp(0, (int)v, 0x112, 0xF, 0xF, false);
  v += (uint32_t)__builtin_amdgcn_update_dpp(0, (int)v, 0x114, 0xF, 0xF, false);
  v += (uint32_t)__builtin_amdgcn_update_dpp(0, (int)v, 0x118, 0xF, 0xF, false);
  v += (uint32_t)__builtin_amdgcn_update_dpp(0, (int)v, 0x142, 0xA, 0xF, false);
  v += (uint32_t)__builtin_amdgcn_update_dpp(0, (int)v, 0x143, 0xC, 0xF, false);
  return v;
}

// integer u64 max (fkey-space can set bit63; f64 trick NOT valid here)
template<int CTRL>
__device__ __forceinline__ uint64_t dpp_max_u64(uint64_t v) {
  uint32_t lo = (uint32_t)v, hi = (uint32_t)(v >> 32);
  uint32_t slo = (uint32_t)__builtin_amdgcn_update_dpp(0, (int)lo, CTRL, 0xF, 0xF, false);
  uint32_t shi = (uint32_t)__builtin_amdgcn_update_dpp(0, (int)hi, CTRL, 0xF, 0xF, false);
  uint64_t o = ((uint64_t)shi << 32) | slo;
  return (o > v) ? o : v;
}
__device__ __forceinline__ uint64_t wave_max_u64(uint64_t v) {
  v = dpp_max_u64<0x111>(v);
  v = dpp_max_u64<0x112>(v);
  v = dpp_max_u64<0x114>(v);
  v = dpp_max_u64<0x118>(v);
  v = dpp_max_u64<0x142>(v);
  v = dpp_max_u64<0x143>(v);
  uint32_t lo = rl((uint32_t)v, 63);
  uint32_t hi = rl((uint32_t)(v >> 32), 63);
  return ((uint64_t)hi << 32) | lo;
}

// One wave per batch element. Beam m's state in lanes with (lane&15)==m
// (replicated 4x). Candidate slot (lane = m+16g, k): symbol c = 32g+k,
// except (g=0,k=0) = unchanged candidate of beam m. 2048 slots exactly.
// DS ordering: per-wave LDS ops execute in order and the compiler keeps
// program order for same-object accesses + inserts counted lgkmcnt waits,
// so no explicit fences are needed for same-wave write->read pairs.
// Theta: 15-stage half-sort (bitonic-64) + two half-cleaners give the
// top-16 multiset replicated in every 16-row; th = row-min (= exact
// rank-15, bit-identical to the full sort) and gmx = row-max (= rank-0)
// without the final 6 sort stages and without any readlane.
__global__ __launch_bounds__(64, 1) void ctc_decode_kernel(
    const float* __restrict__ x, const int* __restrict__ lengths,
    float* __restrict__ out) {
  __shared__ uint64_t surv[64];              // 64 survivors (dump goes to trace)
  __shared__ __align__(16) float Pr[S_];     // pruned probs (single buffer)
  __shared__ __align__(16) uint32_t bstH[32];  // {h_j, h_j*HASHM} pairs
  __shared__ __align__(16) uint32_t bstD[16][4];  // {h, lpack, c0pb, upnb}
  __shared__ __align__(8) uint16_t trace[T_ * 16];  // (parent<<8)|sym per step/beam

  const int b = blockIdx.x;
  const int lane = (int)threadIdx.x;
  const int m = lane & 15;
  const int g = lane >> 4;
  const int lenb = lengths[b];

  uint32_t h = (m == 0) ? 0u : (0x80000000u + (uint32_t)m);
  uint32_t hMreg = h * HASHM;   // loop-carried own-beam h*HASHM
  float pb = (m == 0) ? 1.0f : 0.0f;
  float pnb = 0.0f;
  int last = -1;
  int len = 0;

  // t = 0: load + stage into Pr; prefetch pv/plast; publish bstH
  float plast;
  f4 pv[8];
  {
    const float* xt = x + (size_t)b * S_;
    float a0 = xt[lane], a1 = xt[lane + 64];
    float p0 = (a0 > 0.001f) ? a0 : 0.0f;
    float p1 = (a1 > 0.001f) ? a1 : 0.0f;
    Pr[lane] = p0;
    Pr[lane + 64] = p1;
    if (lane < 16) {
      uint2 w2; w2.x = h; w2.y = hMreg;
      *(uint2*)&bstH[2 * m] = w2;
    }
    const f4* P4 = (const f4*)(Pr + 32 * g);
    #pragma unroll
    for (int i = 0; i < 8; ++i) pv[i] = P4[i];
    plast = Pr[0];  // last == -1 -> index 0
  }

  const uint32_t cbase = 1u + 32u * (uint32_t)g;
  const uint32_t nrefb = ~(15u + (uint32_t)m * 127u + 32u * (uint32_t)g);

  for (int t = 0; t < lenb; ++t) {
    const float* P = Pr;
    // ---- step-top LDS reads (broadcast, pipelined via counted lgkmcnt)
    uint4 hq[8];
    #pragma unroll
    for (int i = 0; i < 8; ++i) hq[i] = ((const uint4*)bstH)[i];
    const float P0 = P[0];
    // prefetch next frame (raw; pruning + staging happen late this step)
    float r0n = 0.0f, r1n = 0.0f;
    const bool hasNext = (t + 1 < lenb);
    if (hasNext) {
      const float* xt = x + ((size_t)(t + 1) * B_ + b) * S_;
      r0n = xt[lane];
      r1n = xt[lane + 64];
    }
    const uint32_t hMc = hMreg + cbase;

    const float ptot = __fadd_rn(pb, pnb);
    const float c0pb = __fmul_rn(P0, ptot);
    const float c0pnb = (last >= 0) ? __fmul_rn(plast, pnb) : 0.0f;

    // ---- fused dup-mask + merge-match detection (register h/hM vectors)
    uint32_t lmask = 0;
    uint32_t matchcnt = 0, jm = 0, cc = 1;
    #pragma unroll
    for (int j = 0; j < 16; ++j) {
      const uint32_t s_h  = (j & 1) ? hq[j >> 1].z : hq[j >> 1].x;
      const uint32_t s_hM = (j & 1) ? hq[j >> 1].w : hq[j >> 1].y;
      // dup: beam j's hash equals my ext (symbol c = s_h - hM - 1)
      uint32_t p = s_h - hMc;
      lmask |= (p < 32u) ? (1u << (p & 31u)) : 0u;
      // merge: my hash equals an ext of beam j
      uint32_t d = h - s_hM;
      bool match = (d - 2u) <= 126u;
      cc = match ? (d - 1u) : cc;
      jm = match ? (uint32_t)j : jm;
      matchcnt += match ? 1u : 0u;
    }

    // ---- merge term: beams have distinct hashes, so >=2 matches is a
    // hash-collision rarity; single-match gather is bit-exact (adding 0.0f
    // to nonneg terms is identity, one nonzero term => order-free).
    float term0;
    if (__builtin_expect(__ballot(matchcnt > 1u) == 0ull, 1)) {
      float tpb = __shfl(pb, (int)jm);
      float tpt = __shfl(ptot, (int)jm);
      int tlast = __shfl(last, (int)jm);
      float tv = P[cc];  // cc==1 when no match; term forced 0 below
      float sel = ((int)cc == tlast) ? tpb : tpt;
      term0 = (matchcnt != 0u) ? __fmul_rn(tv, sel) : 0.0f;
    } else {
      // exact multi-match path (identical to verified full gather + tree)
      float term[16];
      #pragma unroll
      for (int j = 0; j < 16; ++j) {
        uint32_t s_h = rl(h, j);
        uint32_t d = h - s_h * HASHM;
        bool match2 = (d - 2u) <= 126u;
        uint32_t cc2 = match2 ? (d - 1u) : 1u;
        float tv = P[cc2];
        uint32_t slst = rl((uint32_t)last, j);
        float sel = (cc2 == slst) ? rlf(pb, j) : rlf(ptot, j);
        term[j] = match2 ? __fmul_rn(tv, sel) : 0.0f;
      }
      #pragma unroll
      for (int st = 1; st < 16; st <<= 1) {
        #pragma unroll
        for (int i2 = 0; i2 < 16; i2 += 2 * st)
          term[i2] = __fadd_rn(term[i2], term[i2 + st]);
      }
      term0 = term[0];
    }
    const float upnb = __fadd_rn(c0pnb, term0);
    const float key16 = __fadd_rn(c0pb, upnb);

    // ---- publish decode-state now (consumed ~600cy later by decode; all
    // four values are per-beam uniform across the 4 replica lanes)
    if (lane < 16) {
      uint4 w4;
      w4.x = h;
      w4.y = ((uint32_t)(last + 1) & 0xFFu) | ((uint32_t)len << 8);
      w4.z = __float_as_uint(c0pb);
      w4.w = __float_as_uint(upnb);
      *(uint4*)&bstD[m][0] = w4;
    }

    // ---- build 32 candidate keys (floats; dup -> -1.0 sentinel)
    // pv[] was prefetched at the end of the previous step (loop-carried).
    const int lk = last - 32 * g;
    float kf[32];
    #pragma unroll
    for (int k = 0; k < 32; ++k) {
      float pc = pv[k >> 2][k & 3];
      float sel = (k == lk) ? pb : ptot;
      float val = __fmul_rn(pc, sel);
      bool dup = (lmask >> k) & 1u;
      float kv = dup ? -1.0f : val;
      if (k == 0) kv = (lane < 16) ? key16 : kv;
      kf[k] = kv;
    }

    // ---- per-lane max via fmax tree (m2 only needed in rare refine branch)
    float mx[16];
    #pragma unroll
    for (int i = 0; i < 16; ++i) mx[i] = fmaxf(kf[2 * i], kf[2 * i + 1]);
    #pragma unroll
    for (int w2 = 8; w2 >= 1; w2 >>= 1) {
      #pragma unroll
      for (int i = 0; i < w2; ++i) mx[i] = fmaxf(mx[i], mx[i + w2]);
    }
    const float m1 = mx[0];

    // ---- theta: 15-stage half-sort -> bitonic-64; two half-cleaners give
    // the top-16 multiset replicated in EVERY 16-row; th = row-min = exact
    // rank-15 (bit-identical to the full sort), gmx = row-max = rank-0.
    // No readlane: th and scale end up wave-uniform in VGPRs.
    const float hv = bsort_halves_f32(m1, lane);
    const float c1 = fmaxf(hv, bfly_f32<32>(hv));   // top-32 multiset (repl.)
    const float c2 = fmaxf(c1, bfly_f32<16>(c1));   // top-16 multiset (repl.)
    float mn = c2, mxr = c2;
    mn = fminf(mn, bfly_f32<1>(mn));  mxr = fmaxf(mxr, bfly_f32<1>(mxr));
    mn = fminf(mn, bfly_f32<2>(mn));  mxr = fmaxf(mxr, bfly_f32<2>(mxr));
    mn = fminf(mn, bfly_f32<4>(mn));  mxr = fmaxf(mxr, bfly_f32<4>(mxr));
    mn = fminf(mn, bfly_f32<8>(mn));  mxr = fmaxf(mxr, bfly_f32<8>(mxr));
    float th = mn;

    // ---- rescale divisor (global max candidate; uniform, no readlane)
    const float mxf = fmaxf(mxr, 1e-30f);
    const float scale = __fdiv_rn(1.0f, mxf);

    uint32_t gcnt[4];
    #pragma unroll
    for (int grp = 0; grp < 4; ++grp) {
      uint32_t c2c = 0;
      #pragma unroll
      for (int k = grp * 8; k < grp * 8 + 8; ++k) c2c += (kf[k] >= th) ? 1u : 0u;
      gcnt[grp] = c2c;
    }
    uint32_t cnt = (gcnt[0] + gcnt[1]) + (gcnt[2] + gcnt[3]);
    uint32_t incl = incl_scan_add(cnt);
    uint32_t M = rl(incl, 63);

    // ---- refine: theta2 = 8th-largest m2 (8 lanes x top-2 => >=16 >= th2)
    if (__builtin_expect(M > 64u, 0)) {
      // per-lane top-2 tournament (2nd = max3(min(h1,h2), s1, s2))
      float t1[16], t2[16];
      #pragma unroll
      for (int i = 0; i < 16; ++i) {
        float a2 = kf[2 * i], b2 = kf[2 * i + 1];
        t1[i] = fmaxf(a2, b2);
        t2[i] = fminf(a2, b2);
      }
      #pragma unroll
      for (int w2 = 8; w2 >= 1; w2 >>= 1) {
        #pragma unroll
        for (int i = 0; i < w2; ++i) {
          float A = t1[i], Bv = t1[i + w2];
          float sa = t2[i], sb = t2[i + w2];
          t1[i] = fmaxf(A, Bv);
          t2[i] = fmaxf(fminf(A, Bv), fmaxf(sa, sb));
        }
      }
      float th2 = rlf(bsort64_f32(t2[0], lane), 7);
      th = fmaxf(th, th2);
      #pragma unroll
      for (int grp = 0; grp < 4; ++grp) {
        uint32_t c2c = 0;
        #pragma unroll
        for (int k = grp * 8; k < grp * 8 + 8; ++k) c2c += (kf[k] >= th) ? 1u : 0u;
        gcnt[grp] = c2c;
      }
      cnt = (gcnt[0] + gcnt[1]) + (gcnt[2] + gcnt[3]);
      incl = incl_scan_add(cnt);
      M = rl(incl, 63);
    }

    uint64_t selpk;
    if (__builtin_expect(M <= 64u, 1)) {
      // ---- branchless compress into LDS; 4 independent 8-deep pos chains.
      // Dump target = this step's trace region (fully overwritten below).
      uint64_t* dump = (uint64_t*)(&trace[(size_t)t * 16]);
      uint32_t base0 = incl - cnt;
      uint32_t base1 = base0 + gcnt[0];
      uint32_t base2 = base1 + gcnt[1];
      uint32_t base3 = base2 + gcnt[2];
      uint32_t bases[4] = {base0, base1, base2, base3};
      #pragma unroll
      for (int grp = 0; grp < 4; ++grp) {
        uint32_t pos = bases[grp];
        #pragma unroll
        for (int kk = 0; kk < 8; ++kk) {
          int k = grp * 8 + kk;
          bool q = kf[k] >= th;
          uint32_t nr = nrefb - (uint32_t)k;
          if (k == 0) nr = (lane < 16) ? ~(uint32_t)m : nr;
          uint64_t pk = ((uint64_t)__float_as_uint(kf[k]) << 32) | nr;
          uint64_t* dst = q ? &surv[pos] : dump;  // pos < M <= 64 when q
          *dst = pk;
          pos += q ? 1u : 0u;
        }
      }
      // No fence: surv read below may-alias the writes, so the compiler
      // keeps order and emits the counted lgkmcnt; DS pipe is in-order.
      uint64_t w = ((uint32_t)lane < M) ? surv[lane] : 0ull;
      if (M <= 16u)      w = bsortN_u64<16>(w, lane);
      else if (M <= 32u) w = bsortN_u64<32>(w, lane);
      else               w = bsortN_u64<64>(w, lane);
      // broadcast ranks 0..15 (row 0) to all rows: lane gets rank (lane&15)
      uint64_t s16 = bfly_u64<16>(w);
      uint64_t w01 = ((lane & 16) == 0) ? w : s16;
      uint64_t s32 = bfly_u64<32>(w01);
      selpk = ((lane & 32) == 0) ? w01 : s32;
    } else {
      // last-resort exact fallback: 16 rounds of argmax with removal
      uint32_t alive = 0xFFFFFFFFu;
      selpk = 0;
      #pragma unroll 1
      for (int r = 0; r < 16; ++r) {
        float bk = -1.0f;
        uint32_t bi = 0;
        #pragma unroll
        for (int k = 0; k < 32; ++k) {
          float kv = ((alive >> k) & 1u) ? kf[k] : -1.0f;
          if (kv > bk) { bk = kv; bi = (uint32_t)k; }
        }
        uint32_t nr = nrefb - bi;
        nr = (bi == 0u && lane < 16) ? ~(uint32_t)m : nr;
        uint64_t cand = ((uint64_t)fkey(bk) << 32) | nr;
        uint64_t win = wave_max_u64(cand);
        if (cand == win) alive &= ~(1u << bi);
        if (r == m) selpk = win;
      }
      // repack winner key from fkey-space to raw float bits
      uint32_t kb = (uint32_t)(selpk >> 32);
      kb ^= ((int32_t)kb < 0) ? 0x80000000u : 0xFFFFFFFFu;
      selpk = ((uint64_t)kb << 32) | (uint32_t)selpk;
    }

    // ---- stage next frame (in-order DS; all frame-t reads — P0, P[cc],
    //      multi-match gathers — were issued earlier in program order)
    if (hasNext) {
      float p0 = (r0n > 0.001f) ? r0n : 0.0f;
      float p1 = (r1n > 0.001f) ? r1n : 0.0f;
      Pr[lane] = p0;
      Pr[lane + 64] = p1;
    }

    // ---- decode winner -> new beam m state (single b128 gather from bstD)
    const uint32_t gref = ~((uint32_t)selpk);
    const uint32_t keyw = (uint32_t)(selpk >> 32);
    const bool unch = gref < 16u;
    const uint32_t qq = gref - 16u;
    const uint32_t bsrc = qq / 127u;
    const uint32_t jj = qq - bsrc * 127u;
    const uint32_t c = jj + 1u;
    const int srcl = unch ? (int)gref : (int)bsrc;

    const uint4 sd = *(const uint4*)&bstD[srcl][0];
    const uint32_t s_h = sd.x;
    const int s_lst = (int)(sd.y & 0xFFu) - 1;
    const int s_len = (int)(sd.y >> 8);
    const float s_upb = __uint_as_float(sd.z);
    const float s_upn = __uint_as_float(sd.w);

    const uint32_t n_h = unch ? s_h : (s_h * HASHM + (jj + 2u));
    const uint32_t n_hM = n_h * HASHM;
    const float n_pb = unch ? s_upb : 0.0f;
    const float n_pnb = unch ? s_upn : __uint_as_float(keyw);
    const int n_last = unch ? s_lst : (int)c;
    const int n_len = unch ? s_len : (s_len + 1);

    // publish next-step beam hashes (read ~150cy later at next step top)
    if (lane < 16) {
      uint2 w2; w2.x = n_h; w2.y = n_hM;
      *(uint2*)&bstH[2 * m] = w2;
      trace[t * 16 + lane] =
          (uint16_t)(((uint32_t)srcl << 8) | (unch ? 0u : c));
    }

    // ---- rescale (exact, scale precomputed from the theta reduce)
    pb = __fmul_rn(n_pb, scale);
    pnb = __fmul_rn(n_pnb, scale);
    h = n_h; hMreg = n_hM; last = n_last; len = n_len;

    // ---- cross-step prefetch: next step's LDS frame reads issued here so
    // their latency hides under the loop tail + next step's head VALU.
    // Single buffer is safe: staging above already wrote frame t+1, and
    // in-order DS means these reads observe it.
    if (hasNext) {
      const f4* Pn4 = (const f4*)(Pr + 32 * g);
      #pragma unroll
      for (int i = 0; i < 8; ++i) pv[i] = Pn4[i];
      plast = Pr[(last >= 0) ? last : 0];
    }
  }

  __syncthreads();

  float* prefs = out;
  float* lensOut = out + (B_ * T_);
  float* scores = out + (B_ * T_) + B_;

  const int L0 = __shfl(len, 0);
  for (int i = L0 + lane; i < T_; i += 64) prefs[(size_t)b * T_ + i] = -1.0f;

  if (lane == 0) {
    lensOut[b] = (float)L0;
    scores[b] = __fadd_rn(pb, pnb);
    int w = 0;
    int pos2 = L0 - 1;
    for (int t2 = lenb - 1; t2 >= 0; --t2) {
      uint32_t rec = trace[t2 * 16 + w];
      uint32_t sym = rec & 0xFFu;
      if (sym) { prefs[(size_t)b * T_ + pos2] = (float)sym; --pos2; }
      w = (int)(rec >> 8);
    }
  }
}

extern "C" void kernel_launch(void* const* d_in, const int* in_sizes, int n_in,
                              void* d_out, int out_size, void* d_ws, size_t ws_size,
                              hipStream_t stream) {
  (void)in_sizes; (void)n_in; (void)d_ws; (void)ws_size; (void)out_size;
  const float* x = (const float*)d_in[0];
  const int* lengths = (const int*)d_in[1];
  float* out = (float*)d_out;
  ctc_decode_kernel<<<B_, 64, 0, stream>>>(x, lengths, out);
}